// Round 8
// baseline (206.613 us; speedup 1.0000x reference)
//
#include <hip/hip_runtime.h>

#define N_NODES 100000
#define D_IN 32
#define D_HID 64
#define D_OUT 32
#define NBUCK 391      // ceil(N_NODES/256)
#define CHUNK 8192     // edges per partition block
#define CAP   8192     // localfill LDS image capacity (ints)

typedef unsigned short ushort8v __attribute__((ext_vector_type(8)));
typedef unsigned short ushort4v __attribute__((ext_vector_type(4)));

__device__ __forceinline__ float bf2f(unsigned short u) {
    return __uint_as_float((unsigned)u << 16);
}
__device__ __forceinline__ unsigned short f2bf(float f) {
    unsigned u = __float_as_uint(f);
    return (unsigned short)((u + 0x7FFF + ((u >> 16) & 1)) >> 16);   // RTN-even
}

#define RED4(a) { a += __shfl_xor(a, 4); a += __shfl_xor(a, 8); \
                  a += __shfl_xor(a, 16); a += __shfl_xor(a, 32); }

// ---------------- bucket-level histograms (LDS-staged) ----------------
__global__ __launch_bounds__(256) void bucket_hist_kernel(
    const int* __restrict__ src, const int* __restrict__ dst,
    int* __restrict__ sb_cnt, int* __restrict__ db_cnt, int E) {
    __shared__ int hs[NBUCK], hd[NBUCK];
    int tid = threadIdx.x;
    for (int i = tid; i < NBUCK; i += 256) { hs[i] = 0; hd[i] = 0; }
    __syncthreads();
    int stride = gridDim.x * 256;
    for (int e = blockIdx.x * 256 + tid; e < E; e += stride) {
        atomicAdd(&hs[src[e] >> 8], 1);
        atomicAdd(&hd[dst[e] >> 8], 1);
    }
    __syncthreads();
    for (int i = tid; i < NBUCK; i += 256) {
        if (hs[i]) atomicAdd(&sb_cnt[i], hs[i]);
        if (hd[i]) atomicAdd(&db_cnt[i], hd[i]);
    }
}

// ---------------- single-block scan of both bucket counters ----------------
__global__ __launch_bounds__(512) void bucket_scan_kernel(
    const int* __restrict__ sb_cnt, const int* __restrict__ db_cnt,
    int* __restrict__ sb_base, int* __restrict__ db_base,
    int* __restrict__ sb_cur, int* __restrict__ db_cur, int E) {
    __shared__ int s[512];
    int tid = threadIdx.x;
    int v = (tid < NBUCK) ? sb_cnt[tid] : 0;
    s[tid] = v;
    __syncthreads();
    for (int off = 1; off < 512; off <<= 1) {
        int tv = (tid >= off) ? s[tid - off] : 0;
        __syncthreads(); s[tid] += tv; __syncthreads();
    }
    if (tid < NBUCK) { int e0 = s[tid] - v; sb_base[tid] = e0; sb_cur[tid] = e0; }
    if (tid == 0) sb_base[NBUCK] = E;
    __syncthreads();
    int v2 = (tid < NBUCK) ? db_cnt[tid] : 0;
    s[tid] = v2;
    __syncthreads();
    for (int off = 1; off < 512; off <<= 1) {
        int tv = (tid >= off) ? s[tid - off] : 0;
        __syncthreads(); s[tid] += tv; __syncthreads();
    }
    if (tid < NBUCK) { int e0 = s[tid] - v2; db_base[tid] = e0; db_cur[tid] = e0; }
    if (tid == 0) db_base[NBUCK] = E;
}

// ---------------- merged LDS multisplit: dst->ebuf (packed), src->sbuf (bytes) ----------------
__global__ __launch_bounds__(512) void partition_both_kernel(
    const int* __restrict__ src, const int* __restrict__ dst,
    int* __restrict__ sb_cur, int* __restrict__ db_cur,
    int* __restrict__ ebuf, unsigned char* __restrict__ sbuf, int E) {
    __shared__ int dh[NBUCK], sh_[NBUCK];
    __shared__ int sarr[512];
    __shared__ int dloff[NBUCK], dgb[NBUCK], dcur[NBUCK];
    __shared__ int sloff[NBUCK], sgb[NBUCK], scur[NBUCK];
    __shared__ int dbuf[CHUNK];
    __shared__ unsigned char sbytes[CHUNK];
    int tid = threadIdx.x;
    int base = blockIdx.x * CHUNK;
    int lim = E - base; if (lim > CHUNK) lim = CHUNK;

    for (int i = tid; i < NBUCK; i += 512) { dh[i] = 0; sh_[i] = 0; }
    __syncthreads();
    for (int k = tid; k < lim; k += 512) {
        atomicAdd(&dh[dst[base + k] >> 8], 1);
        atomicAdd(&sh_[src[base + k] >> 8], 1);
    }
    __syncthreads();
    int v = (tid < NBUCK) ? dh[tid] : 0;
    sarr[tid] = v;
    __syncthreads();
    for (int off = 1; off < 512; off <<= 1) {
        int tv = (tid >= off) ? sarr[tid - off] : 0;
        __syncthreads(); sarr[tid] += tv; __syncthreads();
    }
    if (tid < NBUCK) {
        int excl = sarr[tid] - v;
        dloff[tid] = excl; dcur[tid] = excl;
        dgb[tid] = v ? atomicAdd(&db_cur[tid], v) : 0;
    }
    __syncthreads();
    int v2 = (tid < NBUCK) ? sh_[tid] : 0;
    sarr[tid] = v2;
    __syncthreads();
    for (int off = 1; off < 512; off <<= 1) {
        int tv = (tid >= off) ? sarr[tid - off] : 0;
        __syncthreads(); sarr[tid] += tv; __syncthreads();
    }
    if (tid < NBUCK) {
        int excl = sarr[tid] - v2;
        sloff[tid] = excl; scur[tid] = excl;
        sgb[tid] = v2 ? atomicAdd(&sb_cur[tid], v2) : 0;
    }
    __syncthreads();
    for (int k = tid; k < lim; k += 512) {
        int d = dst[base + k], s0 = src[base + k];
        int p = atomicAdd(&dcur[d >> 8], 1);
        dbuf[p] = (s0 << 8) | (d & 255);
        int p2 = atomicAdd(&scur[s0 >> 8], 1);
        sbytes[p2] = (unsigned char)(s0 & 255);
    }
    __syncthreads();
    int w = tid >> 6, lane = tid & 63;
    for (int b = w; b < NBUCK; b += 8) {
        int st = dloff[b], len = dh[b], gb = dgb[b];
        for (int i = lane; i < len; i += 64) ebuf[gb + i] = dbuf[st + i];
        int st2 = sloff[b], len2 = sh_[b], gb2 = sgb[b];
        for (int i = lane; i < len2; i += 64) sbuf[gb2 + i] = sbytes[st2 + i];
    }
}

// ---------------- per-bucket src count -> norm_src; xs_bf16 = bf16(x * norm_src) ----------------
__global__ __launch_bounds__(256) void src_norm_prescale_kernel(
    const unsigned char* __restrict__ sbuf, const int* __restrict__ sb_base,
    const float4* __restrict__ x4, ushort4v* __restrict__ xs4b,
    float* __restrict__ norm_src, int n_nodes) {
    __shared__ int cnt[256];
    __shared__ float nsl[256];
    int b = blockIdx.x, tid = threadIdx.x;
    int st = sb_base[b], en = sb_base[b + 1];
    cnt[tid] = 0;
    __syncthreads();
    for (int k = st + tid; k < en; k += 256) atomicAdd(&cnt[sbuf[k]], 1);
    __syncthreads();
    int base_node = b << 8;
    int nn = n_nodes - base_node; if (nn > 256) nn = 256;
    if (tid < nn) {
        int d = cnt[tid];
        float ns = rsqrtf((float)(d < 1 ? 1 : d));
        norm_src[base_node + tid] = ns;
        nsl[tid] = ns;
    }
    __syncthreads();
    for (int k = tid; k < nn * 8; k += 256) {
        float4 v = x4[((long)base_node << 3) + k];
        float s = nsl[k >> 3];
        ushort4v o;
        o[0] = f2bf(v.x * s); o[1] = f2bf(v.y * s);
        o[2] = f2bf(v.z * s); o[3] = f2bf(v.w * s);
        xs4b[((long)base_node << 3) + k] = o;
    }
}

// ---------------- per-bucket: count + scan -> rowptr & norm_dst, fill colidx ----------------
__global__ __launch_bounds__(256) void localfill_kernel(
    const int* __restrict__ ebuf, const int* __restrict__ db_base,
    int* __restrict__ rowptr, float* __restrict__ norm_dst,
    int* __restrict__ colidx, int n_nodes, int E) {
    __shared__ int limg[CAP];
    __shared__ int cnt[256];
    __shared__ int sc[256];
    int b = blockIdx.x, tid = threadIdx.x;
    int base_node = b << 8;
    int nn = n_nodes - base_node; if (nn > 256) nn = 256;
    int cbase = db_base[b], cend = db_base[b + 1];
    int len = cend - cbase;
    cnt[tid] = 0;
    __syncthreads();
    for (int k = tid; k < len; k += 256) atomicAdd(&cnt[ebuf[cbase + k] & 255], 1);
    __syncthreads();
    int v = cnt[tid];
    sc[tid] = v;
    __syncthreads();
    for (int off = 1; off < 256; off <<= 1) {
        int tv = (tid >= off) ? sc[tid - off] : 0;
        __syncthreads(); sc[tid] += tv; __syncthreads();
    }
    int excl = sc[tid] - v;
    if (tid < nn) {
        rowptr[base_node + tid] = cbase + excl;
        norm_dst[base_node + tid] = rsqrtf((float)(v < 1 ? 1 : v));
    }
    if (b == NBUCK - 1 && tid == 0) rowptr[n_nodes] = E;
    __syncthreads();
    cnt[tid] = excl;   // reuse as local cursor
    __syncthreads();
    if (len <= CAP) {
        for (int k = tid; k < len; k += 256) {
            int v2 = ebuf[cbase + k];
            int p = atomicAdd(&cnt[v2 & 255], 1);
            limg[p] = v2 >> 8;
        }
        __syncthreads();
        for (int k = tid; k < len; k += 256) colidx[cbase + k] = limg[k];
    } else {
        for (int k = tid; k < len; k += 256) {
            int v2 = ebuf[cbase + k];
            int p = atomicAdd(&cnt[v2 & 255], 1);
            colidx[cbase + p] = v2 >> 8;
        }
    }
}

// ---------------- layer 1 fused: bf16 gather (16 slots x 4 lanes) + GEMM1 + GEMM2 -> y_bf16 ----------------
__global__ __launch_bounds__(256) void layer1_fused(
    const ushort8v* __restrict__ xs8, const int* __restrict__ colidx,
    const int* __restrict__ rowptr, const float* __restrict__ norm_src,
    const float* __restrict__ norm_dst,
    const float* __restrict__ W1, const float* __restrict__ b1,
    const float* __restrict__ W2, unsigned short* __restrict__ ybf, int n_nodes) {
    __shared__ float W1s[D_IN * D_HID];
    __shared__ float W2s[D_HID * D_OUT];
    __shared__ float b1s[D_HID];
    __shared__ float accs[4][D_IN];
    __shared__ float z1s[4][D_HID];
    int t = threadIdx.x;
    for (int i = t; i < 2048; i += 256) { W1s[i] = W1[i]; W2s[i] = W2[i]; }
    if (t < D_HID) b1s[t] = b1[t];
    __syncthreads();

    int w = t >> 6, lane = t & 63;
    int eh = lane >> 2;          // edge slot (0..15)
    int q  = lane & 3;           // 16B chunk of 64B row
    int j  = lane & 31;          // GEMM2 output feature
    int kb = (lane >> 5) * 32;   // GEMM2 k-half base

    for (int n = blockIdx.x * 4 + w; n < n_nodes; n += gridDim.x * 4) {
        int start = rowptr[n], deg = rowptr[n + 1] - start;
        float a[8];
#pragma unroll
        for (int r = 0; r < 8; ++r) a[r] = 0.f;
        for (int base = 0; base < deg; base += 64) {
            int rem = deg - base;
            int lim = rem < 64 ? rem : 64;
            int lim_up = (lim + 15) & ~15;
            int c_reg = (lane < lim) ? colidx[start + base + lane] : 0;
            for (int i = eh; i < lim_up; i += 16) {
                int c = __shfl(c_reg, i);
                if (i < lim) {
                    ushort8v v = xs8[(long)c * 4 + q];
#pragma unroll
                    for (int r = 0; r < 8; ++r) a[r] += bf2f(v[r]);
                }
            }
        }
#pragma unroll
        for (int r = 0; r < 8; ++r) RED4(a[r])
        if (lane < 4) {
#pragma unroll
            for (int r = 0; r < 8; ++r) accs[w][lane * 8 + r] = a[r];
        }
        float nd = norm_dst[n];
        float s1 = 0.f;
#pragma unroll
        for (int k = 0; k < D_IN; ++k) s1 = fmaf(accs[w][k], W1s[k * D_HID + lane], s1);
        z1s[w][lane] = nd * s1 + b1s[lane];
        float s2 = 0.f;
#pragma unroll
        for (int kk = 0; kk < 32; ++kk) s2 = fmaf(z1s[w][kb + kk], W2s[(kb + kk) * D_OUT + j], s2);
        s2 += __shfl_xor(s2, 32);
        if (lane < 32) ybf[(long)n * D_OUT + j] = f2bf(norm_src[n] * s2);
    }
}

// ---------------- layer 2: bf16 gather (16 slots x 4 lanes) + scale + bias -> out (f32) ----------------
__global__ __launch_bounds__(256) void agg2_kernel(
    const ushort8v* __restrict__ y8, const int* __restrict__ colidx,
    const int* __restrict__ rowptr, const float* __restrict__ norm_dst,
    const float* __restrict__ b2, float* __restrict__ out, int n_nodes) {
    __shared__ float b2s[D_OUT];
    int t = threadIdx.x;
    if (t < D_OUT) b2s[t] = b2[t];
    __syncthreads();
    int w = t >> 6, lane = t & 63;
    int eh = lane >> 2, q = lane & 3;
    for (int n = blockIdx.x * 4 + w; n < n_nodes; n += gridDim.x * 4) {
        int start = rowptr[n], deg = rowptr[n + 1] - start;
        float a[8];
#pragma unroll
        for (int r = 0; r < 8; ++r) a[r] = 0.f;
        for (int base = 0; base < deg; base += 64) {
            int rem = deg - base;
            int lim = rem < 64 ? rem : 64;
            int lim_up = (lim + 15) & ~15;
            int c_reg = (lane < lim) ? colidx[start + base + lane] : 0;
            for (int i = eh; i < lim_up; i += 16) {
                int c = __shfl(c_reg, i);
                if (i < lim) {
                    ushort8v v = y8[(long)c * 4 + q];
#pragma unroll
                    for (int r = 0; r < 8; ++r) a[r] += bf2f(v[r]);
                }
            }
        }
#pragma unroll
        for (int r = 0; r < 8; ++r) RED4(a[r])
        if (lane < 4) {
            float nd = norm_dst[n];
            float* orow = out + (long)n * D_OUT + lane * 8;
            float4 o1, o2;
            o1.x = fmaf(a[0], nd, b2s[lane * 8 + 0]);
            o1.y = fmaf(a[1], nd, b2s[lane * 8 + 1]);
            o1.z = fmaf(a[2], nd, b2s[lane * 8 + 2]);
            o1.w = fmaf(a[3], nd, b2s[lane * 8 + 3]);
            o2.x = fmaf(a[4], nd, b2s[lane * 8 + 4]);
            o2.y = fmaf(a[5], nd, b2s[lane * 8 + 5]);
            o2.z = fmaf(a[6], nd, b2s[lane * 8 + 6]);
            o2.w = fmaf(a[7], nd, b2s[lane * 8 + 7]);
            ((float4*)orow)[0] = o1;
            ((float4*)orow)[1] = o2;
        }
    }
}

extern "C" void kernel_launch(void* const* d_in, const int* in_sizes, int n_in,
                              void* d_out, int out_size, void* d_ws, size_t ws_size,
                              hipStream_t stream) {
    const float* x   = (const float*)d_in[0];
    const int*   src = (const int*)d_in[1];
    const int*   dst = (const int*)d_in[2];
    const float* W1  = (const float*)d_in[3];
    const float* b1  = (const float*)d_in[4];
    const float* W2  = (const float*)d_in[5];
    const float* b2  = (const float*)d_in[6];

    const int N = N_NODES;
    const int E = in_sizes[1];   // 1,600,000

    // workspace layout (ints; every region 16-byte aligned)
    int* ws_i    = (int*)d_ws;
    int* sb_cnt  = ws_i;                   // [512]
    int* db_cnt  = ws_i + 512;             // [512]
    int* sb_base = ws_i + 1024;            // [512]
    int* db_base = ws_i + 1536;            // [512]
    int* sb_cur  = ws_i + 2048;            // [512]
    int* db_cur  = ws_i + 2560;            // [512]
    int* rowptr  = ws_i + 3072;            // [N+4]
    int* colidx  = ws_i + 3072 + N + 4;    // [E]
    float* norms = (float*)(colidx + E);   // [2N]: norm_src | norm_dst
    int* ebuf    = (int*)(norms + 2 * N);  // [E] ints; ybf overlays after localfill
    unsigned char* sbuf = (unsigned char*)(ebuf + E);          // [E] bytes
    unsigned short* xsb = (unsigned short*)(sbuf + E);         // [32N] bf16
    unsigned short* ybf = (unsigned short*)ebuf;               // [32N] bf16 (overlay)

    hipMemsetAsync(ws_i, 0, 1024 * sizeof(int), stream);

    bucket_hist_kernel<<<256, 256, 0, stream>>>(src, dst, sb_cnt, db_cnt, E);
    bucket_scan_kernel<<<1, 512, 0, stream>>>(sb_cnt, db_cnt, sb_base, db_base,
                                              sb_cur, db_cur, E);

    int pb = (E + CHUNK - 1) / CHUNK;      // 196 blocks
    partition_both_kernel<<<pb, 512, 0, stream>>>(src, dst, sb_cur, db_cur,
                                                  ebuf, sbuf, E);
    src_norm_prescale_kernel<<<NBUCK, 256, 0, stream>>>(sbuf, sb_base,
                                                        (const float4*)x, (ushort4v*)xsb,
                                                        norms, N);
    localfill_kernel<<<NBUCK, 256, 0, stream>>>(ebuf, db_base, rowptr, norms + N,
                                                colidx, N, E);

    layer1_fused<<<2048, 256, 0, stream>>>((const ushort8v*)xsb, colidx, rowptr,
                                           norms, norms + N, W1, b1, W2, ybf, N);
    agg2_kernel<<<2048, 256, 0, stream>>>((const ushort8v*)ybf, colidx, rowptr,
                                          norms + N, b2, (float*)d_out, N);
}

// Round 9
// 183.577 us; speedup vs baseline: 1.1255x; 1.1255x over previous
//
#include <hip/hip_runtime.h>

#define N_NODES 100000
#define D_IN 32
#define D_HID 64
#define D_OUT 32
#define NBUCK 391      // ceil(N_NODES/256)
#define CHUNK 8192     // edges per partition block
#define CAP   8192     // localfill LDS image capacity (ints)

typedef unsigned short ushort8v __attribute__((ext_vector_type(8)));
typedef unsigned short ushort4v __attribute__((ext_vector_type(4)));

__device__ __forceinline__ float bf2f(unsigned short u) {
    return __uint_as_float((unsigned)u << 16);
}
__device__ __forceinline__ unsigned short f2bf(float f) {
    unsigned u = __float_as_uint(f);
    return (unsigned short)((u + 0x7FFF + ((u >> 16) & 1)) >> 16);   // RTN-even
}

#define REDH(a) { a += __shfl_xor(a, 4); a += __shfl_xor(a, 8); a += __shfl_xor(a, 16); }

// ---------------- bucket-level histograms (LDS-staged) ----------------
__global__ __launch_bounds__(256) void bucket_hist_kernel(
    const int* __restrict__ src, const int* __restrict__ dst,
    int* __restrict__ sb_cnt, int* __restrict__ db_cnt, int E) {
    __shared__ int hs[NBUCK], hd[NBUCK];
    int tid = threadIdx.x;
    for (int i = tid; i < NBUCK; i += 256) { hs[i] = 0; hd[i] = 0; }
    __syncthreads();
    int stride = gridDim.x * 256;
    for (int e = blockIdx.x * 256 + tid; e < E; e += stride) {
        atomicAdd(&hs[src[e] >> 8], 1);
        atomicAdd(&hd[dst[e] >> 8], 1);
    }
    __syncthreads();
    for (int i = tid; i < NBUCK; i += 256) {
        if (hs[i]) atomicAdd(&sb_cnt[i], hs[i]);
        if (hd[i]) atomicAdd(&db_cnt[i], hd[i]);
    }
}

// ---------------- single-block scan of both bucket counters ----------------
__global__ __launch_bounds__(512) void bucket_scan_kernel(
    const int* __restrict__ sb_cnt, const int* __restrict__ db_cnt,
    int* __restrict__ sb_base, int* __restrict__ db_base,
    int* __restrict__ sb_cur, int* __restrict__ db_cur, int E) {
    __shared__ int s[512];
    int tid = threadIdx.x;
    int v = (tid < NBUCK) ? sb_cnt[tid] : 0;
    s[tid] = v;
    __syncthreads();
    for (int off = 1; off < 512; off <<= 1) {
        int tv = (tid >= off) ? s[tid - off] : 0;
        __syncthreads(); s[tid] += tv; __syncthreads();
    }
    if (tid < NBUCK) { int e0 = s[tid] - v; sb_base[tid] = e0; sb_cur[tid] = e0; }
    if (tid == 0) sb_base[NBUCK] = E;
    __syncthreads();
    int v2 = (tid < NBUCK) ? db_cnt[tid] : 0;
    s[tid] = v2;
    __syncthreads();
    for (int off = 1; off < 512; off <<= 1) {
        int tv = (tid >= off) ? s[tid - off] : 0;
        __syncthreads(); s[tid] += tv; __syncthreads();
    }
    if (tid < NBUCK) { int e0 = s[tid] - v2; db_base[tid] = e0; db_cur[tid] = e0; }
    if (tid == 0) db_base[NBUCK] = E;
}

// ---------------- merged LDS multisplit: dst->ebuf (packed), src->sbuf (bytes) ----------------
__global__ __launch_bounds__(512) void partition_both_kernel(
    const int* __restrict__ src, const int* __restrict__ dst,
    int* __restrict__ sb_cur, int* __restrict__ db_cur,
    int* __restrict__ ebuf, unsigned char* __restrict__ sbuf, int E) {
    __shared__ int dh[NBUCK], sh_[NBUCK];
    __shared__ int sarr[512];
    __shared__ int dloff[NBUCK], dgb[NBUCK], dcur[NBUCK];
    __shared__ int sloff[NBUCK], sgb[NBUCK], scur[NBUCK];
    __shared__ int dbuf[CHUNK];
    __shared__ unsigned char sbytes[CHUNK];
    int tid = threadIdx.x;
    int base = blockIdx.x * CHUNK;
    int lim = E - base; if (lim > CHUNK) lim = CHUNK;

    for (int i = tid; i < NBUCK; i += 512) { dh[i] = 0; sh_[i] = 0; }
    __syncthreads();
    for (int k = tid; k < lim; k += 512) {
        atomicAdd(&dh[dst[base + k] >> 8], 1);
        atomicAdd(&sh_[src[base + k] >> 8], 1);
    }
    __syncthreads();
    int v = (tid < NBUCK) ? dh[tid] : 0;
    sarr[tid] = v;
    __syncthreads();
    for (int off = 1; off < 512; off <<= 1) {
        int tv = (tid >= off) ? sarr[tid - off] : 0;
        __syncthreads(); sarr[tid] += tv; __syncthreads();
    }
    if (tid < NBUCK) {
        int excl = sarr[tid] - v;
        dloff[tid] = excl; dcur[tid] = excl;
        dgb[tid] = v ? atomicAdd(&db_cur[tid], v) : 0;
    }
    __syncthreads();
    int v2 = (tid < NBUCK) ? sh_[tid] : 0;
    sarr[tid] = v2;
    __syncthreads();
    for (int off = 1; off < 512; off <<= 1) {
        int tv = (tid >= off) ? sarr[tid - off] : 0;
        __syncthreads(); sarr[tid] += tv; __syncthreads();
    }
    if (tid < NBUCK) {
        int excl = sarr[tid] - v2;
        sloff[tid] = excl; scur[tid] = excl;
        sgb[tid] = v2 ? atomicAdd(&sb_cur[tid], v2) : 0;
    }
    __syncthreads();
    for (int k = tid; k < lim; k += 512) {
        int d = dst[base + k], s0 = src[base + k];
        int p = atomicAdd(&dcur[d >> 8], 1);
        dbuf[p] = (s0 << 8) | (d & 255);
        int p2 = atomicAdd(&scur[s0 >> 8], 1);
        sbytes[p2] = (unsigned char)(s0 & 255);
    }
    __syncthreads();
    int w = tid >> 6, lane = tid & 63;
    for (int b = w; b < NBUCK; b += 8) {
        int st = dloff[b], len = dh[b], gb = dgb[b];
        for (int i = lane; i < len; i += 64) ebuf[gb + i] = dbuf[st + i];
        int st2 = sloff[b], len2 = sh_[b], gb2 = sgb[b];
        for (int i = lane; i < len2; i += 64) sbuf[gb2 + i] = sbytes[st2 + i];
    }
}

// ---------------- per-bucket src count -> norm_src; xs_bf16 = bf16(x * norm_src) ----------------
__global__ __launch_bounds__(256) void src_norm_prescale_kernel(
    const unsigned char* __restrict__ sbuf, const int* __restrict__ sb_base,
    const float4* __restrict__ x4, ushort4v* __restrict__ xs4b,
    float* __restrict__ norm_src, int n_nodes) {
    __shared__ int cnt[256];
    __shared__ float nsl[256];
    int b = blockIdx.x, tid = threadIdx.x;
    int st = sb_base[b], en = sb_base[b + 1];
    cnt[tid] = 0;
    __syncthreads();
    for (int k = st + tid; k < en; k += 256) atomicAdd(&cnt[sbuf[k]], 1);
    __syncthreads();
    int base_node = b << 8;
    int nn = n_nodes - base_node; if (nn > 256) nn = 256;
    if (tid < nn) {
        int d = cnt[tid];
        float ns = rsqrtf((float)(d < 1 ? 1 : d));
        norm_src[base_node + tid] = ns;
        nsl[tid] = ns;
    }
    __syncthreads();
    for (int k = tid; k < nn * 8; k += 256) {
        float4 v = x4[((long)base_node << 3) + k];
        float s = nsl[k >> 3];
        ushort4v o;
        o[0] = f2bf(v.x * s); o[1] = f2bf(v.y * s);
        o[2] = f2bf(v.z * s); o[3] = f2bf(v.w * s);
        xs4b[((long)base_node << 3) + k] = o;
    }
}

// ---------------- per-bucket: count + scan -> rowptr & norm_dst, fill colidx ----------------
__global__ __launch_bounds__(256) void localfill_kernel(
    const int* __restrict__ ebuf, const int* __restrict__ db_base,
    int* __restrict__ rowptr, float* __restrict__ norm_dst,
    int* __restrict__ colidx, int n_nodes, int E) {
    __shared__ int limg[CAP];
    __shared__ int cnt[256];
    __shared__ int sc[256];
    int b = blockIdx.x, tid = threadIdx.x;
    int base_node = b << 8;
    int nn = n_nodes - base_node; if (nn > 256) nn = 256;
    int cbase = db_base[b], cend = db_base[b + 1];
    int len = cend - cbase;
    cnt[tid] = 0;
    __syncthreads();
    for (int k = tid; k < len; k += 256) atomicAdd(&cnt[ebuf[cbase + k] & 255], 1);
    __syncthreads();
    int v = cnt[tid];
    sc[tid] = v;
    __syncthreads();
    for (int off = 1; off < 256; off <<= 1) {
        int tv = (tid >= off) ? sc[tid - off] : 0;
        __syncthreads(); sc[tid] += tv; __syncthreads();
    }
    int excl = sc[tid] - v;
    if (tid < nn) {
        rowptr[base_node + tid] = cbase + excl;
        norm_dst[base_node + tid] = rsqrtf((float)(v < 1 ? 1 : v));
    }
    if (b == NBUCK - 1 && tid == 0) rowptr[n_nodes] = E;
    __syncthreads();
    cnt[tid] = excl;   // reuse as local cursor
    __syncthreads();
    if (len <= CAP) {
        for (int k = tid; k < len; k += 256) {
            int v2 = ebuf[cbase + k];
            int p = atomicAdd(&cnt[v2 & 255], 1);
            limg[p] = v2 >> 8;
        }
        __syncthreads();
        for (int k = tid; k < len; k += 256) colidx[cbase + k] = limg[k];
    } else {
        for (int k = tid; k < len; k += 256) {
            int v2 = ebuf[cbase + k];
            int p = atomicAdd(&cnt[v2 & 255], 1);
            colidx[cbase + p] = v2 >> 8;
        }
    }
}

// ---------------- layer 1 fused: 2-node bf16 gather + GEMM1 + GEMM2 -> y_bf16 ----------------
// lane: half = lane>>5 (node A/B); within half: eh = slot(0..7), q = 16B chunk(0..3)
__global__ __launch_bounds__(256) void layer1_fused(
    const ushort8v* __restrict__ xs8, const int* __restrict__ colidx,
    const int* __restrict__ rowptr, const float* __restrict__ norm_src,
    const float* __restrict__ norm_dst,
    const float* __restrict__ W1, const float* __restrict__ b1,
    const float* __restrict__ W2, unsigned short* __restrict__ ybf, int n_nodes) {
    __shared__ float W1s[D_IN * D_HID];
    __shared__ float W2s[D_HID * D_OUT];
    __shared__ float b1s[D_HID];
    __shared__ float accs[4][2][D_IN];
    __shared__ float z1s[4][2][D_HID];
    int t = threadIdx.x;
    for (int i = t; i < 2048; i += 256) { W1s[i] = W1[i]; W2s[i] = W2[i]; }
    if (t < D_HID) b1s[t] = b1[t];
    __syncthreads();

    int w = t >> 6, lane = t & 63;
    int half = lane >> 5;
    int hl = lane & 31;
    int eh = hl >> 2;            // edge slot (0..7)
    int q  = hl & 3;             // 16B chunk of 64B row
    int j  = hl;                 // GEMM2 output feature
    int npairs = (n_nodes + 1) >> 1;
    int stride = gridDim.x * 4;

    int p = blockIdx.x * 4 + w;
    int rA = 0, rA1 = 0, rB1 = 0;
    if (p < npairs) {
        rA = rowptr[2 * p]; rA1 = rowptr[2 * p + 1];
        rB1 = (2 * p + 2 <= n_nodes) ? rowptr[2 * p + 2] : rA1;
    }
    while (p < npairs) {
        int np = p + stride;
        int nrA = 0, nrA1 = 0, nrB1 = 0;
        if (np < npairs) {                       // prefetch next pair's rowptr
            nrA = rowptr[2 * np]; nrA1 = rowptr[2 * np + 1];
            nrB1 = (2 * np + 2 <= n_nodes) ? rowptr[2 * np + 2] : nrA1;
        }
        int nA = 2 * p, nB = nA + 1;
        bool hasB = nB < n_nodes;
        int sA = rA, dA = rA1 - rA;
        int sB = rA1, dB = hasB ? (rB1 - rA1) : 0;
        int dmax = dA > dB ? dA : dB;
        int myS = half ? sB : sA;
        int myD = half ? dB : dA;
        float a[8];
#pragma unroll
        for (int r = 0; r < 8; ++r) a[r] = 0.f;
        for (int base = 0; base < dmax; base += 32) {
            int mylim = myD - base; mylim = mylim < 0 ? 0 : (mylim > 32 ? 32 : mylim);
            int c_reg = (hl < mylim) ? colidx[myS + base + hl] : 0;
            int la = dA - base; la = la < 0 ? 0 : (la > 32 ? 32 : la);
            int lb = dB - base; lb = lb < 0 ? 0 : (lb > 32 ? 32 : lb);
            int lm = la > lb ? la : lb;
            int lim_up = (lm + 7) & ~7;
            for (int i = eh; i < lim_up; i += 8) {
                int c = __shfl(c_reg, (half << 5) | i);
                if (i < mylim) {
                    ushort8v v = xs8[(long)c * 4 + q];
#pragma unroll
                    for (int r = 0; r < 8; ++r) a[r] += bf2f(v[r]);
                }
            }
        }
#pragma unroll
        for (int r = 0; r < 8; ++r) REDH(a[r])
        if (hl < 4) {
#pragma unroll
            for (int r = 0; r < 8; ++r) accs[w][half][hl * 8 + r] = a[r];
        }
        float ndA = norm_dst[nA], ndB = hasB ? norm_dst[nB] : 0.f;
        float s1A = 0.f, s1B = 0.f;
#pragma unroll
        for (int k = 0; k < D_IN; ++k) {
            float wv = W1s[k * D_HID + lane];
            s1A = fmaf(accs[w][0][k], wv, s1A);
            s1B = fmaf(accs[w][1][k], wv, s1B);
        }
        z1s[w][0][lane] = ndA * s1A + b1s[lane];
        z1s[w][1][lane] = ndB * s1B + b1s[lane];
        float s2 = 0.f;
#pragma unroll
        for (int k = 0; k < D_HID; ++k) s2 = fmaf(z1s[w][half][k], W2s[k * D_OUT + j], s2);
        int n_ = half ? nB : nA;
        if (!half || hasB) ybf[(long)n_ * D_OUT + j] = f2bf(norm_src[n_] * s2);
        p = np; rA = nrA; rA1 = nrA1; rB1 = nrB1;
    }
}

// ---------------- layer 2: 2-node bf16 gather + scale + bias -> out (f32) ----------------
__global__ __launch_bounds__(256) void agg2_kernel(
    const ushort8v* __restrict__ y8, const int* __restrict__ colidx,
    const int* __restrict__ rowptr, const float* __restrict__ norm_dst,
    const float* __restrict__ b2, float* __restrict__ out, int n_nodes) {
    __shared__ float b2s[D_OUT];
    int t = threadIdx.x;
    if (t < D_OUT) b2s[t] = b2[t];
    __syncthreads();
    int w = t >> 6, lane = t & 63;
    int half = lane >> 5;
    int hl = lane & 31;
    int eh = hl >> 2, q = hl & 3;
    int npairs = (n_nodes + 1) >> 1;
    int stride = gridDim.x * 4;

    int p = blockIdx.x * 4 + w;
    int rA = 0, rA1 = 0, rB1 = 0;
    if (p < npairs) {
        rA = rowptr[2 * p]; rA1 = rowptr[2 * p + 1];
        rB1 = (2 * p + 2 <= n_nodes) ? rowptr[2 * p + 2] : rA1;
    }
    while (p < npairs) {
        int np = p + stride;
        int nrA = 0, nrA1 = 0, nrB1 = 0;
        if (np < npairs) {
            nrA = rowptr[2 * np]; nrA1 = rowptr[2 * np + 1];
            nrB1 = (2 * np + 2 <= n_nodes) ? rowptr[2 * np + 2] : nrA1;
        }
        int nA = 2 * p, nB = nA + 1;
        bool hasB = nB < n_nodes;
        int sA = rA, dA = rA1 - rA;
        int sB = rA1, dB = hasB ? (rB1 - rA1) : 0;
        int dmax = dA > dB ? dA : dB;
        int myS = half ? sB : sA;
        int myD = half ? dB : dA;
        float a[8];
#pragma unroll
        for (int r = 0; r < 8; ++r) a[r] = 0.f;
        for (int base = 0; base < dmax; base += 32) {
            int mylim = myD - base; mylim = mylim < 0 ? 0 : (mylim > 32 ? 32 : mylim);
            int c_reg = (hl < mylim) ? colidx[myS + base + hl] : 0;
            int la = dA - base; la = la < 0 ? 0 : (la > 32 ? 32 : la);
            int lb = dB - base; lb = lb < 0 ? 0 : (lb > 32 ? 32 : lb);
            int lm = la > lb ? la : lb;
            int lim_up = (lm + 7) & ~7;
            for (int i = eh; i < lim_up; i += 8) {
                int c = __shfl(c_reg, (half << 5) | i);
                if (i < mylim) {
                    ushort8v v = y8[(long)c * 4 + q];
#pragma unroll
                    for (int r = 0; r < 8; ++r) a[r] += bf2f(v[r]);
                }
            }
        }
#pragma unroll
        for (int r = 0; r < 8; ++r) REDH(a[r])
        if (hl < 4) {
            int n_ = half ? nB : nA;
            if (!half || hasB) {
                float nd = norm_dst[n_];
                float* orow = out + (long)n_ * D_OUT + hl * 8;
                float4 o1, o2;
                o1.x = fmaf(a[0], nd, b2s[hl * 8 + 0]);
                o1.y = fmaf(a[1], nd, b2s[hl * 8 + 1]);
                o1.z = fmaf(a[2], nd, b2s[hl * 8 + 2]);
                o1.w = fmaf(a[3], nd, b2s[hl * 8 + 3]);
                o2.x = fmaf(a[4], nd, b2s[hl * 8 + 4]);
                o2.y = fmaf(a[5], nd, b2s[hl * 8 + 5]);
                o2.z = fmaf(a[6], nd, b2s[hl * 8 + 6]);
                o2.w = fmaf(a[7], nd, b2s[hl * 8 + 7]);
                ((float4*)orow)[0] = o1;
                ((float4*)orow)[1] = o2;
            }
        }
        p = np; rA = nrA; rA1 = nrA1; rB1 = nrB1;
    }
}

extern "C" void kernel_launch(void* const* d_in, const int* in_sizes, int n_in,
                              void* d_out, int out_size, void* d_ws, size_t ws_size,
                              hipStream_t stream) {
    const float* x   = (const float*)d_in[0];
    const int*   src = (const int*)d_in[1];
    const int*   dst = (const int*)d_in[2];
    const float* W1  = (const float*)d_in[3];
    const float* b1  = (const float*)d_in[4];
    const float* W2  = (const float*)d_in[5];
    const float* b2  = (const float*)d_in[6];

    const int N = N_NODES;
    const int E = in_sizes[1];   // 1,600,000

    // workspace layout (ints; every region 16-byte aligned)
    int* ws_i    = (int*)d_ws;
    int* sb_cnt  = ws_i;                   // [512]
    int* db_cnt  = ws_i + 512;             // [512]
    int* sb_base = ws_i + 1024;            // [512]
    int* db_base = ws_i + 1536;            // [512]
    int* sb_cur  = ws_i + 2048;            // [512]
    int* db_cur  = ws_i + 2560;            // [512]
    int* rowptr  = ws_i + 3072;            // [N+4]
    int* colidx  = ws_i + 3072 + N + 4;    // [E]
    float* norms = (float*)(colidx + E);   // [2N]: norm_src | norm_dst
    int* ebuf    = (int*)(norms + 2 * N);  // [E] ints; ybf overlays after localfill
    unsigned char* sbuf = (unsigned char*)(ebuf + E);          // [E] bytes
    unsigned short* xsb = (unsigned short*)(sbuf + E);         // [32N] bf16
    unsigned short* ybf = (unsigned short*)ebuf;               // [32N] bf16 (overlay)

    hipMemsetAsync(ws_i, 0, 1024 * sizeof(int), stream);

    bucket_hist_kernel<<<256, 256, 0, stream>>>(src, dst, sb_cnt, db_cnt, E);
    bucket_scan_kernel<<<1, 512, 0, stream>>>(sb_cnt, db_cnt, sb_base, db_base,
                                              sb_cur, db_cur, E);

    int pb = (E + CHUNK - 1) / CHUNK;      // 196 blocks
    partition_both_kernel<<<pb, 512, 0, stream>>>(src, dst, sb_cur, db_cur,
                                                  ebuf, sbuf, E);
    src_norm_prescale_kernel<<<NBUCK, 256, 0, stream>>>(sbuf, sb_base,
                                                        (const float4*)x, (ushort4v*)xsb,
                                                        norms, N);
    localfill_kernel<<<NBUCK, 256, 0, stream>>>(ebuf, db_base, rowptr, norms + N,
                                                colidx, N, E);

    layer1_fused<<<2048, 256, 0, stream>>>((const ushort8v*)xsb, colidx, rowptr,
                                           norms, norms + N, W1, b1, W2, ybf, N);
    agg2_kernel<<<2048, 256, 0, stream>>>((const ushort8v*)ybf, colidx, rowptr,
                                          norms + N, b2, (float*)d_out, N);
}